// Round 5
// baseline (445.341 us; speedup 1.0000x reference)
//
#include <hip/hip_runtime.h>

namespace {

constexpr int T   = 2048;
constexpr int B   = 8192;
constexpr int C   = 16;        // steps per chunk / barrier round
constexpr int NCH = T / C;     // 128 chunks
constexpr int NB  = 4;         // h-ring depth (chunks)

// LDS-only barrier: waits lgkmcnt(0), leaves vmcnt alone so loader-wave
// global prefetch stays in flight across rounds (R4-proven).
__device__ __forceinline__ void barrier_nodrain() {
    asm volatile("s_waitcnt lgkmcnt(0)\n\ts_barrier" ::: "memory");
}

struct IzhState {
    float vnp;   // vn of previous step (pre-reset value)
    float up;    // u after previous step
    bool  spp;   // spike of previous step
};

// Select-late Izhikevich step, bit-exact vs reference:
//  - no-spike branch: identical op sequence from vnp (== selected v)
//  - spike branch: v' = -65 (constant) makes m2,s1,s2 fold to K0 with the
//    exact same IEEE roundings at compile time; s3/s4/vn ops identical.
//  - true vn = select(spp, vnS, vnA) == reference's vn from selected v.
// Critical recurrence cycle = 8 ops (was 9); cmp and u-ops sit in slack.
__device__ __forceinline__ bool izh_step(IzhState& s, float I) {
#pragma clang fp contract(off)
    const float K0 = ((0.04f * (-65.0f)) * (-65.0f) + (5.0f * (-65.0f))) + 140.0f;
    float m2a = 0.04f * s.vnp;
    float m2  = m2a * s.vnp;
    float f5  = 5.0f * s.vnp;
    float s2A = (m2 + f5) + 140.0f;
    float s3A = s2A - s.up;
    float s4A = s3A + I;
    float vnA = s.vnp + s4A;        // no-spike continuation
    float s3S = K0 - s.up;
    float s4S = s3S + I;
    float vnS = (-65.0f) + s4S;     // post-spike continuation (3 ops from u)
    float vn  = s.spp ? vnS : vnA;  // the only on-chain select
    bool  sp  = (vn >= 30.0f);
    float m4  = 0.2f * vn;          // u update, reference order
    float s5  = m4 - s.up;
    float tt  = 0.02f * s5;
    float un  = s.up + tt;
    float d8  = sp ? 8.0f : 0.0f;   // z*8 exact incl. +/-0 (R3/R4-proven)
    s.up  = un + d8;
    s.vnp = vn;
    s.spp = sp;
    return sp;
}

// 5-wave specialized block (64 batch elems):
//  wid 0/1: hidden-neuron recurrences (lean: LDS h in, spike out)
//  wid 2  : output recurrence + global store
//  wid 3/4: loaders — global x + linear layer -> LDS h-ring (parallel in t)
__global__ __launch_bounds__(320, 1) void izh5(
    const float* __restrict__ xs,
    const float* __restrict__ W_in, const float* __restrict__ b_in,
    const float* __restrict__ W_out, const float* __restrict__ b_out,
    float* __restrict__ out)
{
    __shared__ float hbuf[2][NB][C][64];   // 32 KB: h ring, filled 2 chunks ahead
    __shared__ float sbuf[2][2][C][64];    // 16 KB: hidden spikes, double-buffered

    const int lane = threadIdx.x & 63;
    const int wid  = threadIdx.x >> 6;
    const int b    = blockIdx.x * 64 + lane;

    if (wid >= 3) {
        // ---------------- loader / linear waves ----------------
#pragma clang fp contract(off)
        const int w = wid - 3;   // 0 or 1: handles chunks with m&1 == w
        const float w00 = W_in[0], w01 = W_in[1], w02 = W_in[2], w03 = W_in[3];
        const float w10 = W_in[4], w11 = W_in[5], w12 = W_in[6], w13 = W_in[7];
        const float bi0 = b_in[0], bi1 = b_in[1];
        const float4* xp = reinterpret_cast<const float4*>(xs) + b;

        auto fill = [&](int m) {
#pragma clang fp contract(off)
            const int slot = m & (NB - 1);
            float4 xv[C];
#pragma unroll
            for (int j = 0; j < C; ++j) xv[j] = xp[(size_t)(m * C + j) * B];
#pragma unroll
            for (int j = 0; j < C; ++j) {
                const float4 x = xv[j];
                float h0 = (((x.x * w00) + (x.y * w01)) + (x.z * w02)) + (x.w * w03);
                h0 = h0 + bi0;
                float h1 = (((x.x * w10) + (x.y * w11)) + (x.z * w12)) + (x.w * w13);
                h1 = h1 + bi1;
                hbuf[0][slot][j][lane] = h0;
                hbuf[1][slot][j][lane] = h1;
            }
        };

        fill(w);                 // prologue: chunks 0 (loader0) and 1 (loader1)
        barrier_nodrain();
        for (int r = 0; r <= NCH; ++r) {
            const int m = r + 2; // stay 2 chunks ahead of the rec waves
            if (m < NCH && (m & 1) == w) fill(m);
            barrier_nodrain();
        }
    } else if (wid < 2) {
        // ---------------- hidden recurrence waves ----------------
#pragma clang fp contract(off)
        IzhState st{-65.0f, -13.0f, true};   // spp=true makes t=0 exact
        barrier_nodrain();
        for (int r = 0; r <= NCH; ++r) {
            if (r < NCH) {
                const int slot = r & (NB - 1);
                const int par  = r & 1;
                float Iv[C];
#pragma unroll
                for (int j = 0; j < C; ++j) Iv[j] = hbuf[wid][slot][j][lane];
#pragma unroll
                for (int j = 0; j < C; ++j) {
                    bool sp = izh_step(st, Iv[j]);
                    sbuf[wid][par][j][lane] = sp ? 1.0f : 0.0f;
                }
            }
            barrier_nodrain();
        }
    } else {
        // ---------------- output recurrence wave (lags 1 chunk) ----------------
#pragma clang fp contract(off)
        const float wo0 = W_out[0], wo1 = W_out[1], bo = b_out[0];
        // y for z in {0,1}^2 with the reference's exact op order (R3-proven).
        const float c00 = ((0.0f * wo0) + (0.0f * wo1)) + bo;
        const float c10 = ((1.0f * wo0) + (0.0f * wo1)) + bo;
        const float c01 = ((0.0f * wo0) + (1.0f * wo1)) + bo;
        const float c11 = ((1.0f * wo0) + (1.0f * wo1)) + bo;
        float* op = out + b;
        IzhState st{-65.0f, -13.0f, true};
        barrier_nodrain();
        for (int r = 0; r <= NCH; ++r) {
            if (r >= 1) {
                const int c   = r - 1;
                const int par = c & 1;
                float z0[C], z1[C];
#pragma unroll
                for (int j = 0; j < C; ++j) {
                    z0[j] = sbuf[0][par][j][lane];
                    z1[j] = sbuf[1][par][j][lane];
                }
#pragma unroll
                for (int j = 0; j < C; ++j) {
                    float yt = (z1[j] != 0.0f) ? c11 : c10;
                    float yf = (z1[j] != 0.0f) ? c01 : c00;
                    float y  = (z0[j] != 0.0f) ? yt : yf;
                    bool spo = izh_step(st, y);
                    op[(size_t)(c * C + j) * B] = spo ? 1.0f : 0.0f;
                }
            }
            barrier_nodrain();
        }
    }
}

} // namespace

extern "C" void kernel_launch(void* const* d_in, const int* in_sizes, int n_in,
                              void* d_out, int out_size, void* d_ws, size_t ws_size,
                              hipStream_t stream) {
    const float* xs    = (const float*)d_in[0];
    const float* W_in  = (const float*)d_in[1];
    const float* b_in  = (const float*)d_in[2];
    const float* W_out = (const float*)d_in[3];
    const float* b_out = (const float*)d_in[4];
    float* out = (float*)d_out;

    dim3 grid(B / 64), block(320);   // 128 blocks x 5 waves
    hipLaunchKernelGGL(izh5, grid, block, 0, stream,
                       xs, W_in, b_in, W_out, b_out, out);
}

// Round 6
// 431.483 us; speedup vs baseline: 1.0321x; 1.0321x over previous
//
#include <hip/hip_runtime.h>

namespace {

constexpr int T   = 2048;
constexpr int B   = 8192;
constexpr int C   = 32;        // steps per barrier round (R4 was 16 — halve round count)
constexpr int NCH = T / C;     // 64 rounds
constexpr int RD  = 16;        // x prefetch register-ring depth (~16*60cyc >= HBM latency)

// LDS-only barrier: waits lgkmcnt(0), leaves vmcnt alone so global prefetch
// stays in flight across rounds (R4-proven).
__device__ __forceinline__ void barrier_nodrain() {
    asm volatile("s_waitcnt lgkmcnt(0)\n\ts_barrier" ::: "memory");
}

struct IzhState {
    float vnp;   // vn of previous step (pre-reset value)
    float up;    // u after previous step
    bool  spp;   // spike of previous step
};

// Select-late Izhikevich step (R5-validated bit-exact, absmax==0.0):
// spike-branch v'=-65 is constant, so its quadratic folds to K0 at compile
// time with identical IEEE rounding; only one cndmask sits on the v-cycle.
// Critical recurrence cycle = 8 ops.
__device__ __forceinline__ bool izh_step(IzhState& s, float I) {
#pragma clang fp contract(off)
    const float K0 = ((0.04f * (-65.0f)) * (-65.0f) + (5.0f * (-65.0f))) + 140.0f;
    float m2a = 0.04f * s.vnp;
    float m2  = m2a * s.vnp;
    float f5  = 5.0f * s.vnp;
    float s2A = (m2 + f5) + 140.0f;
    float s3A = s2A - s.up;
    float s4A = s3A + I;
    float vnA = s.vnp + s4A;        // no-spike continuation
    float s3S = K0 - s.up;
    float s4S = s3S + I;
    float vnS = (-65.0f) + s4S;     // post-spike continuation
    float vn  = s.spp ? vnS : vnA;  // the only on-chain select
    bool  sp  = (vn >= 30.0f);
    float m4  = 0.2f * vn;          // u update, reference op order
    float s5  = m4 - s.up;
    float tt  = 0.02f * s5;
    float un  = s.up + tt;
    float d8  = sp ? 8.0f : 0.0f;   // z*8 exact incl. +/-0
    s.up  = un + d8;
    s.vnp = vn;
    s.spp = sp;
    return sp;
}

// 3-wave block (R4 structure, which beat the 5-wave split):
//  wid 0/1: hidden neuron recurrences (own x loads + linear + izh)
//  wid 2  : output recurrence, lags one round, stores result
__global__ __launch_bounds__(192, 1) void izh3b(
    const float* __restrict__ xs,
    const float* __restrict__ W_in, const float* __restrict__ b_in,
    const float* __restrict__ W_out, const float* __restrict__ b_out,
    float* __restrict__ out)
{
    __shared__ float zbuf[2][2][C][64];   // 32 KB: [neuron][parity][step][lane]
    const int lane = threadIdx.x & 63;
    const int wid  = threadIdx.x >> 6;
    const int b    = blockIdx.x * 64 + lane;

    if (wid < 2) {
        // ---------------- hidden producer for neuron `wid` ----------------
#pragma clang fp contract(off)
        const float wa = W_in[wid * 4 + 0], wb = W_in[wid * 4 + 1];
        const float wc = W_in[wid * 4 + 2], wd = W_in[wid * 4 + 3];
        const float bi = b_in[wid];
        const float4* xp = reinterpret_cast<const float4*>(xs) + b;

        // Depth-16 register ring, refill same slot at consume (R2/R4-proven).
        float4 ring[RD];
#pragma unroll
        for (int i = 0; i < RD; ++i) ring[i] = xp[(size_t)i * B];

        IzhState st{-65.0f, -13.0f, true};   // spp=true reproduces t=0 exactly
        for (int r = 0; r < NCH; ++r) {
            const int p = r & 1;
#pragma unroll
            for (int j = 0; j < C; ++j) {
                const int t = r * C + j;
                const float4 x = ring[j & (RD - 1)];
                // refill 16 steps ahead; wrap at end (harmless, avoids branch)
                ring[j & (RD - 1)] = xp[(size_t)((t + RD) & (T - 1)) * B];
                float h = (((x.x * wa) + (x.y * wb)) + (x.z * wc)) + (x.w * wd);
                h = h + bi;
                bool sp = izh_step(st, h);
                zbuf[wid][p][j][lane] = sp ? 1.0f : 0.0f;
            }
            barrier_nodrain();
        }
    } else {
        // ---------------- output recurrence (lags 1 round) ----------------
#pragma clang fp contract(off)
        const float wo0 = W_out[0], wo1 = W_out[1], bo = b_out[0];
        // y = ((z0*wo0)+(z1*wo1))+bo for z in {0,1}^2, reference's exact op
        // order -> 4 bit-identical constants, selected per step (R3-proven).
        const float c00 = ((0.0f * wo0) + (0.0f * wo1)) + bo;
        const float c10 = ((1.0f * wo0) + (0.0f * wo1)) + bo;
        const float c01 = ((0.0f * wo0) + (1.0f * wo1)) + bo;
        const float c11 = ((1.0f * wo0) + (1.0f * wo1)) + bo;
        float* op = out + b;
        IzhState st{-65.0f, -13.0f, true};

        auto consume = [&](int kk) {
#pragma clang fp contract(off)
            const int p = kk & 1;
            float z0[C], z1[C];
#pragma unroll
            for (int j = 0; j < C; ++j) {
                z0[j] = zbuf[0][p][j][lane];
                z1[j] = zbuf[1][p][j][lane];
            }
#pragma unroll
            for (int j = 0; j < C; ++j) {
                float yt = (z1[j] != 0.0f) ? c11 : c10;
                float yf = (z1[j] != 0.0f) ? c01 : c00;
                float y  = (z0[j] != 0.0f) ? yt : yf;
                bool spo = izh_step(st, y);
                op[(size_t)(kk * C + j) * B] = spo ? 1.0f : 0.0f;
            }
        };

        for (int r = 0; r < NCH; ++r) {
            if (r > 0) consume(r - 1);   // wave-uniform branch
            barrier_nodrain();
        }
        consume(NCH - 1);                // epilogue: last round, no barrier
    }
}

} // namespace

extern "C" void kernel_launch(void* const* d_in, const int* in_sizes, int n_in,
                              void* d_out, int out_size, void* d_ws, size_t ws_size,
                              hipStream_t stream) {
    const float* xs    = (const float*)d_in[0];
    const float* W_in  = (const float*)d_in[1];
    const float* b_in  = (const float*)d_in[2];
    const float* W_out = (const float*)d_in[3];
    const float* b_out = (const float*)d_in[4];
    float* out = (float*)d_out;

    dim3 grid(B / 64), block(192);   // 128 blocks x 3 waves
    hipLaunchKernelGGL(izh3b, grid, block, 0, stream,
                       xs, W_in, b_in, W_out, b_out, out);
}